// Round 3
// baseline (830.880 us; speedup 1.0000x reference)
//
#include <hip/hip_runtime.h>
#include <hip/hip_bf16.h>
#include <math.h>
#include <stdint.h>

#define B_     16
#define CI_    512
#define CO_    512
#define HH     64
#define WW     64
#define STYLE_ 512

typedef __bf16 bf16x8 __attribute__((ext_vector_type(8)));
typedef float f32x4 __attribute__((ext_vector_type(4)));

// ---- workspace layout (bytes) ----
#define WS_S     0                    // s[b][ci] f32, 32 KB
#define WS_DEMOD 32768                // demod[b][co] f32, 32 KB
#define WS_WSQ   65536                // wsq[ci][co] f32, 1 MB
#define WS_WB    1114112              // wb[t][co][ci] bf16, 4.7 MB
#define WS_XS    5832704              // xs[b][66][x][ci] bf16 (guard rows y=-1,64), 69.2 MB

__device__ __forceinline__ void gload16(const void* g, void* l) {
    __builtin_amdgcn_global_load_lds((const __attribute__((address_space(1))) uint32_t*)g,
                                     (__attribute__((address_space(3))) uint32_t*)l, 16, 0, 0);
}

// ---------- s[b][ci] = style[b] . mod_w[ci] / sqrt(512) + mod_b[ci]
__global__ void k_style(const float* __restrict__ style, const float* __restrict__ mod_w,
                        const float* __restrict__ mod_b, float* __restrict__ s_out) {
    int b  = blockIdx.x;
    int ci = threadIdx.x;
    const float scale = 0.044194173824159216f; // 1/sqrt(512)
    float acc = 0.f;
    const float* st = style + b * STYLE_;
    const float* mw = mod_w + (size_t)ci * STYLE_;
    for (int j = 0; j < STYLE_; ++j) acc += st[j] * mw[j];
    s_out[b * CI_ + ci] = acc * scale + mod_b[ci];
}

// ---------- wsq[ci][co] = sum_tap weight[co][ci][t]^2
__global__ void k_wsq(const float* __restrict__ weight, float* __restrict__ wsq) {
    int p = blockIdx.x * blockDim.x + threadIdx.x; // co*512 + ci
    int co = p >> 9, ci = p & 511;
    const float* wp = weight + (size_t)p * 9;
    float acc = 0.f;
    for (int t = 0; t < 9; ++t) { float v = wp[t]; acc += v * v; }
    wsq[(size_t)ci * CO_ + co] = acc;
}

// ---------- demod[b][co] = rsqrt(w_scale^2 * sum_ci s^2 * wsq + 1e-8)
__global__ void k_demod(const float* __restrict__ s, const float* __restrict__ wsq,
                        float* __restrict__ demod) {
    int b = blockIdx.x, co = threadIdx.x;
    const float w_scale2 = 1.0f / 4608.0f;
    float acc = 0.f;
    const float* sb = s + b * CI_;
    for (int ci = 0; ci < CI_; ++ci) { float sv = sb[ci]; acc += sv * sv * wsq[(size_t)ci * CO_ + co]; }
    demod[b * CO_ + co] = 1.0f / sqrtf(acc * w_scale2 + 1e-8f);
}

// ---------- wb[t][co][ci] = bf16(weight[co][ci][t])
__global__ __launch_bounds__(256) void k_wb(const float* __restrict__ weight, __bf16* __restrict__ wb) {
    int p = blockIdx.x * 256 + threadIdx.x;   // co*512 + ci
    int co = p >> 9, ci = p & 511;
    const float* wp = weight + (size_t)p * 9;
    #pragma unroll
    for (int t = 0; t < 9; ++t)
        wb[((size_t)t * CO_ + co) * CI_ + ci] = (__bf16)wp[t];
}

// ---------- zero guard rows (y = -1 and y = 64) of padded xs
__global__ __launch_bounds__(256) void k_guard(uint32_t* __restrict__ xs32) {
    int b = blockIdx.y;
    int i = blockIdx.x * 256 + threadIdx.x;    // 0..16383 dwords per row
    xs32[((size_t)b * 66 + 0)  * 16384 + i] = 0;
    xs32[((size_t)b * 66 + 65) * 16384 + i] = 0;
}

// ---------- xs[b][y+1][x][ci] = bf16(x[b][ci][y][x] * s[b][ci] * w_scale)  (NHWC, padded rows)
__global__ __launch_bounds__(256) void k_xs(const float* __restrict__ x, const float* __restrict__ s,
                                            __bf16* __restrict__ xs) {
    __shared__ float Lt[64][65];
    const int y = blockIdx.x, b = blockIdx.y;
    const int tid = threadIdx.x;
    const float w_scale = 0.014731391274719739f; // 1/sqrt(512*9)
    for (int ci0 = 0; ci0 < CI_; ci0 += 64) {
        for (int i = tid; i < 64 * 64; i += 256) {
            int ci = i >> 6, xx = i & 63;
            Lt[ci][xx] = x[((size_t)(b * CI_ + ci0 + ci) * HH + y) * WW + xx]
                         * s[b * CI_ + ci0 + ci] * w_scale;
        }
        __syncthreads();
        for (int o = tid; o < 512; o += 256) {
            int xx = o >> 3, oct = o & 7;
            bf16x8 v;
            #pragma unroll
            for (int j = 0; j < 8; ++j) v[j] = (__bf16)Lt[oct * 8 + j][xx];
            *(bf16x8*)&xs[((((size_t)b * 66 + y + 1) * WW + xx) << 9) + ci0 + oct * 8] = v;
        }
        __syncthreads();
    }
}

// ---------- conv: bf16 implicit GEMM, global_load_lds staging + XOR-swizzled LDS
// block: 256 thr, tile 64co x 8y x 64x; wave wy owns rows y0+2wy..+1 (64co x 128 N)
// LDS: X[10 rowblk][66 xr][32 ci] linear quads, W[9][64][32]; swizzle quad^=(row>>1)&3
#define XBYTES 42240   // 10*66*64
#define WBYTES 36864   // 9*64*64

__global__ __launch_bounds__(256, 2) void k_conv(
    const __bf16* __restrict__ xs, const __bf16* __restrict__ wb,
    const float* __restrict__ demod, float* __restrict__ out)
{
    __shared__ __align__(128) char smem[XBYTES + WBYTES];
    __bf16* ldsX = (__bf16*)smem;
    __bf16* ldsW = (__bf16*)(smem + XBYTES);

    const int tid  = threadIdx.x;
    const int lane = tid & 63;
    const int wave = tid >> 6;
    const int co0  = blockIdx.x * 64;
    const int y0   = blockIdx.y * 8;
    const int b    = blockIdx.z;

    const int m  = lane & 15;
    const int g  = lane >> 4;
    const int qA = g ^ ((m >> 1) & 3);     // W-read quad position (lane const)

    // zero x-halo rows (xr = 0, 65) of each of 10 row-blocks: 20 rows x 16 dwords
    for (int i = tid; i < 320; i += 256) {
        int row20 = i >> 4, dw = i & 15;
        int r = row20 >> 1, c = row20 & 1;
        ((uint32_t*)smem)[(r * 66 + c * 65) * 16 + dw] = 0;
    }

    f32x4 acc[4][8];
    #pragma unroll
    for (int mi = 0; mi < 4; ++mi)
        #pragma unroll
        for (int nt = 0; nt < 8; ++nt) acc[mi][nt] = (f32x4){0.f, 0.f, 0.f, 0.f};

    for (int ci0 = 0; ci0 < CI_; ci0 += 32) {
        // ---- stage X: 10 row-blocks x 4 segs, DMA 1 KB per wave-op
        #pragma unroll
        for (int it = 0; it < 10; ++it) {
            int j = it * 4 + wave;            // 0..39
            int r = j >> 2, seg = j & 3;
            int p = seg * 64 + lane;          // quad index within row-block
            int xr = 1 + (p >> 2), qd = p & 3;
            int rowg = r * 66 + xr;
            int sq = qd ^ ((rowg >> 1) & 3);  // pre-swizzled source quad
            const __bf16* src = xs + ((((size_t)(b * 66 + y0 + r)) * 64 + (xr - 1)) << 9) + ci0 + sq * 8;
            gload16(src, smem + (r * 66 + 1) * 64 + seg * 1024);
        }
        // ---- stage W: 36 segs of 1 KB
        #pragma unroll
        for (int it = 0; it < 9; ++it) {
            int j = it * 4 + wave;            // 0..35
            int p = j * 64 + lane;
            int row = p >> 2, qd = p & 3;     // row = t*64 + co
            int sq = qd ^ ((row >> 1) & 3);
            const __bf16* src = wb + (((size_t)(row >> 6) * CO_ + co0 + (row & 63)) << 9) + ci0 + sq * 8;
            gload16(src, smem + XBYTES + j * 1024);
        }
        __syncthreads();

        // ---- compute: 9 taps x (4 A + 8 x (1 B + 4 MFMA)) = 288 MFMA / 108 b128 reads
        #pragma unroll
        for (int kh = 0; kh < 3; ++kh) {
            #pragma unroll
            for (int kw = 0; kw < 3; ++kw) {
                const int t = kh * 3 + kw;
                bf16x8 a0 = *(const bf16x8*)&ldsW[(t * 64 +  0 + m) * 32 + qA * 8];
                bf16x8 a1 = *(const bf16x8*)&ldsW[(t * 64 + 16 + m) * 32 + qA * 8];
                bf16x8 a2 = *(const bf16x8*)&ldsW[(t * 64 + 32 + m) * 32 + qA * 8];
                bf16x8 a3 = *(const bf16x8*)&ldsW[(t * 64 + 48 + m) * 32 + qA * 8];
                #pragma unroll
                for (int nt = 0; nt < 8; ++nt) {
                    const int ysub = nt >> 2, xt = nt & 3;
                    const int rowg = (wave * 2 + ysub + kh) * 66 + xt * 16 + m + kw;
                    const int qB = g ^ ((rowg >> 1) & 3);
                    bf16x8 bv = *(const bf16x8*)&ldsX[rowg * 32 + qB * 8];
                    acc[0][nt] = __builtin_amdgcn_mfma_f32_16x16x32_bf16(a0, bv, acc[0][nt], 0, 0, 0);
                    acc[1][nt] = __builtin_amdgcn_mfma_f32_16x16x32_bf16(a1, bv, acc[1][nt], 0, 0, 0);
                    acc[2][nt] = __builtin_amdgcn_mfma_f32_16x16x32_bf16(a2, bv, acc[2][nt], 0, 0, 0);
                    acc[3][nt] = __builtin_amdgcn_mfma_f32_16x16x32_bf16(a3, bv, acc[3][nt], 0, 0, 0);
                }
            }
        }
        __syncthreads();
    }

    // ---- epilogue: out[b][co][y][x] = acc * demod[b][co]
    #pragma unroll
    for (int mi = 0; mi < 4; ++mi) {
        #pragma unroll
        for (int j = 0; j < 4; ++j) {
            const int co = co0 + mi * 16 + g * 4 + j;
            const float dm = demod[b * CO_ + co];
            #pragma unroll
            for (int nt = 0; nt < 8; ++nt) {
                const int y = y0 + wave * 2 + (nt >> 2);
                const int xcol = (nt & 3) * 16 + m;
                out[(((size_t)(b * CO_ + co)) * HH + y) * WW + xcol] = acc[mi][nt][j] * dm;
            }
        }
    }
}

extern "C" void kernel_launch(void* const* d_in, const int* in_sizes, int n_in,
                              void* d_out, int out_size, void* d_ws, size_t ws_size,
                              hipStream_t stream) {
    const float* x      = (const float*)d_in[0];
    const float* style  = (const float*)d_in[1];
    const float* weight = (const float*)d_in[2];
    const float* mod_w  = (const float*)d_in[3];
    const float* mod_b  = (const float*)d_in[4];
    float* out = (float*)d_out;

    char* wsb = (char*)d_ws;
    float*  s_buf = (float*)(wsb + WS_S);
    float*  demod = (float*)(wsb + WS_DEMOD);
    float*  wsq   = (float*)(wsb + WS_WSQ);
    __bf16* wb    = (__bf16*)(wsb + WS_WB);
    __bf16* xs    = (__bf16*)(wsb + WS_XS);

    k_style<<<dim3(B_), dim3(CI_), 0, stream>>>(style, mod_w, mod_b, s_buf);
    k_wsq<<<dim3(CO_ * CI_ / 512), dim3(512), 0, stream>>>(weight, wsq);
    k_demod<<<dim3(B_), dim3(CO_), 0, stream>>>(s_buf, wsq, demod);
    k_wb<<<dim3(CO_ * CI_ / 256), dim3(256), 0, stream>>>(weight, wb);
    k_guard<<<dim3(64, B_), dim3(256), 0, stream>>>((uint32_t*)xs);
    k_xs<<<dim3(HH, B_), dim3(256), 0, stream>>>(x, s_buf, xs);
    k_conv<<<dim3(CO_ / 64, HH / 8, B_), dim3(256), 0, stream>>>(xs, wb, demod, out);
}

// Round 4
// 818.177 us; speedup vs baseline: 1.0155x; 1.0155x over previous
//
#include <hip/hip_runtime.h>
#include <hip/hip_bf16.h>
#include <math.h>
#include <stdint.h>

#define B_     16
#define CI_    512
#define CO_    512
#define HH     64
#define WW     64
#define STYLE_ 512

typedef __bf16 bf16x8 __attribute__((ext_vector_type(8)));
typedef float f32x4 __attribute__((ext_vector_type(4)));

// ---- workspace layout (bytes) ----
#define WS_S     0                    // s[b][ci] f32, 32 KB
#define WS_DEMOD 32768                // demod[b][co] f32, 32 KB
#define WS_WSQ   65536                // wsq[ci][co] f32, 1 MB
#define WS_WB    1114112              // wb[ci/32][t][co][32] bf16, 4.7 MB
#define WS_XS    5832704              // xs[ci/32][b][66][x][32] bf16 (guard rows), 69.2 MB

__device__ __forceinline__ void gload16(const void* g, void* l) {
    __builtin_amdgcn_global_load_lds((const __attribute__((address_space(1))) uint32_t*)g,
                                     (__attribute__((address_space(3))) uint32_t*)l, 16, 0, 0);
}

// ---------- s[b][ci] = style[b] . mod_w[ci] / sqrt(512) + mod_b[ci]
__global__ void k_style(const float* __restrict__ style, const float* __restrict__ mod_w,
                        const float* __restrict__ mod_b, float* __restrict__ s_out) {
    int b  = blockIdx.x;
    int ci = threadIdx.x;
    const float scale = 0.044194173824159216f; // 1/sqrt(512)
    float acc = 0.f;
    const float* st = style + b * STYLE_;
    const float* mw = mod_w + (size_t)ci * STYLE_;
    for (int j = 0; j < STYLE_; ++j) acc += st[j] * mw[j];
    s_out[b * CI_ + ci] = acc * scale + mod_b[ci];
}

// ---------- wsq[ci][co] = sum_tap weight[co][ci][t]^2
__global__ void k_wsq(const float* __restrict__ weight, float* __restrict__ wsq) {
    int p = blockIdx.x * blockDim.x + threadIdx.x; // co*512 + ci
    int co = p >> 9, ci = p & 511;
    const float* wp = weight + (size_t)p * 9;
    float acc = 0.f;
    for (int t = 0; t < 9; ++t) { float v = wp[t]; acc += v * v; }
    wsq[(size_t)ci * CO_ + co] = acc;
}

// ---------- demod[b][co] = rsqrt(w_scale^2 * sum_ci s^2 * wsq + 1e-8)
__global__ void k_demod(const float* __restrict__ s, const float* __restrict__ wsq,
                        float* __restrict__ demod) {
    int b = blockIdx.x, co = threadIdx.x;
    const float w_scale2 = 1.0f / 4608.0f;
    float acc = 0.f;
    const float* sb = s + b * CI_;
    for (int ci = 0; ci < CI_; ++ci) { float sv = sb[ci]; acc += sv * sv * wsq[(size_t)ci * CO_ + co]; }
    demod[b * CO_ + co] = 1.0f / sqrtf(acc * w_scale2 + 1e-8f);
}

// ---------- wb[ci>>5][t][co][ci&31] = bf16(weight[co][ci][t])  (chunk-outer layout)
__global__ __launch_bounds__(256) void k_wb(const float* __restrict__ weight, __bf16* __restrict__ wb) {
    int p = blockIdx.x * 256 + threadIdx.x;   // co*512 + ci
    int co = p >> 9, ci = p & 511;
    const float* wp = weight + (size_t)p * 9;
    #pragma unroll
    for (int t = 0; t < 9; ++t)
        wb[((((size_t)(ci >> 5) * 9 + t) * CO_) + co) * 32 + (ci & 31)] = (__bf16)wp[t];
}

// ---------- zero guard rows (padded y = 0 and 65) of chunk-outer xs
__global__ __launch_bounds__(256) void k_guard(uint32_t* __restrict__ xs32) {
    int i = blockIdx.x * 256 + threadIdx.x;   // 0..524287
    int dw = i & 1023, row2 = (i >> 10) & 1, b = (i >> 11) & 15, chunk = i >> 15;
    xs32[(((size_t)chunk * 16 + b) * 66 + row2 * 65) * 1024 + dw] = 0;
}

// ---------- xs[ci>>5][b][y+1][x][ci&31] = bf16(x[b][ci][y][x] * s[b][ci] * w_scale)
__global__ __launch_bounds__(256) void k_xs(const float* __restrict__ x, const float* __restrict__ s,
                                            __bf16* __restrict__ xs) {
    __shared__ float Lt[64][65];
    const int y = blockIdx.x, b = blockIdx.y;
    const int tid = threadIdx.x;
    const float w_scale = 0.014731391274719739f; // 1/sqrt(512*9)
    for (int ci0 = 0; ci0 < CI_; ci0 += 64) {
        for (int i = tid; i < 64 * 64; i += 256) {
            int ci = i >> 6, xx = i & 63;
            Lt[ci][xx] = x[((size_t)(b * CI_ + ci0 + ci) * HH + y) * WW + xx]
                         * s[b * CI_ + ci0 + ci] * w_scale;
        }
        __syncthreads();
        for (int o = tid; o < 512; o += 256) {
            int xx = o >> 3, oct = o & 7;
            int cb = ci0 + oct * 8;
            bf16x8 v;
            #pragma unroll
            for (int j = 0; j < 8; ++j) v[j] = (__bf16)Lt[oct * 8 + j][xx];
            size_t idx = ((((size_t)(cb >> 5) * 16 + b) * 66 + (y + 1)) * 64 + xx) * 32 + (cb & 31);
            *(bf16x8*)&xs[idx] = v;
        }
        __syncthreads();
    }
}

// ---------- conv: bf16 implicit GEMM, global_load_lds staging + XOR-swizzled LDS
// 1024 blocks 1D, XCD-aware remap: r=bid&7 (XCD), q=bid>>3; co_tile=q&7, pair=(q>>3)|(r<<4)
// block tile 64co x 8y x 64x; wave owns 64co x (2y x 64x)
#define XBYTES 42240   // 10*66*64
#define WBYTES 36864   // 9*64*64

__global__ __launch_bounds__(256, 2) void k_conv(
    const __bf16* __restrict__ xs, const __bf16* __restrict__ wb,
    const float* __restrict__ demod, float* __restrict__ out)
{
    __shared__ __align__(128) char smem[XBYTES + WBYTES];
    __bf16* ldsX = (__bf16*)smem;
    __bf16* ldsW = (__bf16*)(smem + XBYTES);

    const int tid  = threadIdx.x;
    const int lane = tid & 63;
    const int wave = tid >> 6;

    const int bid  = blockIdx.x;
    const int r8   = bid & 7;            // XCD
    const int q    = bid >> 3;
    const int co0  = (q & 7) * 64;
    const int pair = (q >> 3) | (r8 << 4);
    const int y0   = (pair & 7) * 8;
    const int b    = pair >> 3;

    const int m  = lane & 15;
    const int g  = lane >> 4;
    const int qA = g ^ ((m >> 1) & 3);     // W-read quad position (lane const)

    f32x4 acc[4][8];
    #pragma unroll
    for (int mi = 0; mi < 4; ++mi)
        #pragma unroll
        for (int nt = 0; nt < 8; ++nt) acc[mi][nt] = (f32x4){0.f, 0.f, 0.f, 0.f};

    // zero x-halo rows (xr = 0, 65) of each of 10 row-blocks: 20 rows x 16 dwords
    for (int i = tid; i < 320; i += 256) {
        int row20 = i >> 4, dw = i & 15;
        int rr = row20 >> 1, c = row20 & 1;
        ((uint32_t*)smem)[(rr * 66 + c * 65) * 16 + dw] = 0;
    }

    for (int ci0 = 0; ci0 < CI_; ci0 += 32) {
        const int chunk = ci0 >> 5;
        // ---- stage X: 10 row-blocks x 4 segs, DMA 1 KB per wave-op
        const __bf16* xsc = xs + ((size_t)chunk * 16 + b) * 66 * 64 * 32;
        #pragma unroll
        for (int it = 0; it < 10; ++it) {
            int j = it * 4 + wave;            // 0..39
            int rr = j >> 2, seg = j & 3;
            int p = seg * 64 + lane;          // quad index within row-block
            int xr = 1 + (p >> 2), qd = p & 3;
            int rowg = rr * 66 + xr;
            int sq = qd ^ ((rowg >> 1) & 3);  // pre-swizzled source quad
            const __bf16* src = xsc + (((y0 + rr) * 64 + (xr - 1)) << 5) + sq * 8;
            gload16(src, smem + (rr * 66 + 1) * 64 + seg * 1024);
        }
        // ---- stage W: 36 segs of 1 KB
        const __bf16* wbc = wb + (size_t)chunk * 9 * CO_ * 32;
        #pragma unroll
        for (int it = 0; it < 9; ++it) {
            int j = it * 4 + wave;            // 0..35
            int p = j * 64 + lane;
            int row = p >> 2, qd = p & 3;     // row = t*64 + co
            int sq = qd ^ ((row >> 1) & 3);
            const __bf16* src = wbc + (((row >> 6) * CO_ + co0 + (row & 63)) << 5) + sq * 8;
            gload16(src, smem + XBYTES + j * 1024);
        }
        __syncthreads();

        // ---- compute: 9 taps x (4 A + 8 x (1 B + 4 MFMA)) = 288 MFMA / 108 b128 reads
        #pragma unroll
        for (int kh = 0; kh < 3; ++kh) {
            #pragma unroll
            for (int kw = 0; kw < 3; ++kw) {
                const int t = kh * 3 + kw;
                bf16x8 a0 = *(const bf16x8*)&ldsW[(t * 64 +  0 + m) * 32 + qA * 8];
                bf16x8 a1 = *(const bf16x8*)&ldsW[(t * 64 + 16 + m) * 32 + qA * 8];
                bf16x8 a2 = *(const bf16x8*)&ldsW[(t * 64 + 32 + m) * 32 + qA * 8];
                bf16x8 a3 = *(const bf16x8*)&ldsW[(t * 64 + 48 + m) * 32 + qA * 8];
                #pragma unroll
                for (int nt = 0; nt < 8; ++nt) {
                    const int ysub = nt >> 2, xt = nt & 3;
                    const int rowg = (wave * 2 + ysub + kh) * 66 + xt * 16 + m + kw;
                    const int qB = g ^ ((rowg >> 1) & 3);
                    bf16x8 bv = *(const bf16x8*)&ldsX[rowg * 32 + qB * 8];
                    acc[0][nt] = __builtin_amdgcn_mfma_f32_16x16x32_bf16(a0, bv, acc[0][nt], 0, 0, 0);
                    acc[1][nt] = __builtin_amdgcn_mfma_f32_16x16x32_bf16(a1, bv, acc[1][nt], 0, 0, 0);
                    acc[2][nt] = __builtin_amdgcn_mfma_f32_16x16x32_bf16(a2, bv, acc[2][nt], 0, 0, 0);
                    acc[3][nt] = __builtin_amdgcn_mfma_f32_16x16x32_bf16(a3, bv, acc[3][nt], 0, 0, 0);
                }
            }
        }
        __syncthreads();
    }

    // ---- epilogue: out[b][co][y][x] = acc * demod[b][co]
    #pragma unroll
    for (int mi = 0; mi < 4; ++mi) {
        #pragma unroll
        for (int j = 0; j < 4; ++j) {
            const int co = co0 + mi * 16 + g * 4 + j;
            const float dm = demod[b * CO_ + co];
            #pragma unroll
            for (int nt = 0; nt < 8; ++nt) {
                const int y = y0 + wave * 2 + (nt >> 2);
                const int xcol = (nt & 3) * 16 + m;
                out[(((size_t)(b * CO_ + co)) * HH + y) * WW + xcol] = acc[mi][nt][j] * dm;
            }
        }
    }
}

extern "C" void kernel_launch(void* const* d_in, const int* in_sizes, int n_in,
                              void* d_out, int out_size, void* d_ws, size_t ws_size,
                              hipStream_t stream) {
    const float* x      = (const float*)d_in[0];
    const float* style  = (const float*)d_in[1];
    const float* weight = (const float*)d_in[2];
    const float* mod_w  = (const float*)d_in[3];
    const float* mod_b  = (const float*)d_in[4];
    float* out = (float*)d_out;

    char* wsb = (char*)d_ws;
    float*  s_buf = (float*)(wsb + WS_S);
    float*  demod = (float*)(wsb + WS_DEMOD);
    float*  wsq   = (float*)(wsb + WS_WSQ);
    __bf16* wb    = (__bf16*)(wsb + WS_WB);
    __bf16* xs    = (__bf16*)(wsb + WS_XS);

    k_style<<<dim3(B_), dim3(CI_), 0, stream>>>(style, mod_w, mod_b, s_buf);
    k_wsq<<<dim3(CO_ * CI_ / 512), dim3(512), 0, stream>>>(weight, wsq);
    k_demod<<<dim3(B_), dim3(CO_), 0, stream>>>(s_buf, wsq, demod);
    k_wb<<<dim3(CO_ * CI_ / 256), dim3(256), 0, stream>>>(weight, wb);
    k_guard<<<dim3(2048), dim3(256), 0, stream>>>((uint32_t*)xs);
    k_xs<<<dim3(HH, B_), dim3(256), 0, stream>>>(x, s_buf, xs);
    k_conv<<<dim3(1024), dim3(256), 0, stream>>>(xs, wb, demod, out);
}

// Round 5
// 341.138 us; speedup vs baseline: 2.4356x; 2.3984x over previous
//
#include <hip/hip_runtime.h>
#include <hip/hip_bf16.h>
#include <math.h>
#include <stdint.h>

#define B_     16
#define CI_    512
#define CO_    512
#define HH     64
#define WW     64
#define STYLE_ 512

typedef __bf16 bf16x8 __attribute__((ext_vector_type(8)));
typedef float f32x4 __attribute__((ext_vector_type(4)));

// ---- workspace layout (bytes) ----
#define WS_S     0                    // s[b][ci] f32, 32 KB
#define WS_DEMOD 32768                // demod[b][co] f32, 32 KB
#define WS_WSQ   65536                // wsq[ci][co] f32, 1 MB
#define WS_WB    1114112              // wb[ci/32][t][co][32] bf16, 4.7 MB
#define WS_XS    5832704              // xs[ci/32][b][66][x][32] bf16 (guard rows), 69.2 MB

__device__ __forceinline__ void gload16(const void* g, void* l) {
    __builtin_amdgcn_global_load_lds((const __attribute__((address_space(1))) uint32_t*)g,
                                     (__attribute__((address_space(3))) uint32_t*)l, 16, 0, 0);
}

// ---------- s[b][ci] = style[b] . mod_w[ci] / sqrt(512) + mod_b[ci]
__global__ void k_style(const float* __restrict__ style, const float* __restrict__ mod_w,
                        const float* __restrict__ mod_b, float* __restrict__ s_out) {
    int b  = blockIdx.x;
    int ci = threadIdx.x;
    const float scale = 0.044194173824159216f; // 1/sqrt(512)
    float acc = 0.f;
    const float* st = style + b * STYLE_;
    const float* mw = mod_w + (size_t)ci * STYLE_;
    for (int j = 0; j < STYLE_; ++j) acc += st[j] * mw[j];
    s_out[b * CI_ + ci] = acc * scale + mod_b[ci];
}

// ---------- wsq[ci][co] = sum_tap weight[co][ci][t]^2
__global__ void k_wsq(const float* __restrict__ weight, float* __restrict__ wsq) {
    int p = blockIdx.x * blockDim.x + threadIdx.x; // co*512 + ci
    int co = p >> 9, ci = p & 511;
    const float* wp = weight + (size_t)p * 9;
    float acc = 0.f;
    for (int t = 0; t < 9; ++t) { float v = wp[t]; acc += v * v; }
    wsq[(size_t)ci * CO_ + co] = acc;
}

// ---------- demod[b][co] = rsqrt(w_scale^2 * sum_ci s^2 * wsq + 1e-8)
__global__ void k_demod(const float* __restrict__ s, const float* __restrict__ wsq,
                        float* __restrict__ demod) {
    int b = blockIdx.x, co = threadIdx.x;
    const float w_scale2 = 1.0f / 4608.0f;
    float acc = 0.f;
    const float* sb = s + b * CI_;
    for (int ci = 0; ci < CI_; ++ci) { float sv = sb[ci]; acc += sv * sv * wsq[(size_t)ci * CO_ + co]; }
    demod[b * CO_ + co] = 1.0f / sqrtf(acc * w_scale2 + 1e-8f);
}

// ---------- wb[ci>>5][t][co][ci&31] = bf16(weight[co][ci][t])  (chunk-outer layout)
__global__ __launch_bounds__(256) void k_wb(const float* __restrict__ weight, __bf16* __restrict__ wb) {
    int p = blockIdx.x * 256 + threadIdx.x;   // co*512 + ci
    int co = p >> 9, ci = p & 511;
    const float* wp = weight + (size_t)p * 9;
    #pragma unroll
    for (int t = 0; t < 9; ++t)
        wb[((((size_t)(ci >> 5) * 9 + t) * CO_) + co) * 32 + (ci & 31)] = (__bf16)wp[t];
}

// ---------- zero guard rows (padded y = 0 and 65) of chunk-outer xs
__global__ __launch_bounds__(256) void k_guard(uint32_t* __restrict__ xs32) {
    int i = blockIdx.x * 256 + threadIdx.x;   // 0..524287
    int dw = i & 1023, row2 = (i >> 10) & 1, b = (i >> 11) & 15, chunk = i >> 15;
    xs32[(((size_t)chunk * 16 + b) * 66 + row2 * 65) * 1024 + dw] = 0;
}

// ---------- xs[ci>>5][b][y+1][x][ci&31] = bf16(x[b][ci][y][x] * s[b][ci] * w_scale)
__global__ __launch_bounds__(256) void k_xs(const float* __restrict__ x, const float* __restrict__ s,
                                            __bf16* __restrict__ xs) {
    __shared__ float Lt[64][65];
    const int y = blockIdx.x, b = blockIdx.y;
    const int tid = threadIdx.x;
    const float w_scale = 0.014731391274719739f; // 1/sqrt(512*9)
    for (int ci0 = 0; ci0 < CI_; ci0 += 64) {
        for (int i = tid; i < 64 * 64; i += 256) {
            int ci = i >> 6, xx = i & 63;
            Lt[ci][xx] = x[((size_t)(b * CI_ + ci0 + ci) * HH + y) * WW + xx]
                         * s[b * CI_ + ci0 + ci] * w_scale;
        }
        __syncthreads();
        for (int o = tid; o < 512; o += 256) {
            int xx = o >> 3, oct = o & 7;
            int cb = ci0 + oct * 8;
            bf16x8 v;
            #pragma unroll
            for (int j = 0; j < 8; ++j) v[j] = (__bf16)Lt[oct * 8 + j][xx];
            size_t idx = ((((size_t)(cb >> 5) * 16 + b) * 66 + (y + 1)) * 64 + xx) * 32 + (cb & 31);
            *(bf16x8*)&xs[idx] = v;
        }
        __syncthreads();
    }
}

// ---------- conv: bf16 implicit GEMM, dbuf LDS + counted vmcnt + raw barriers (T3/T4)
// 1024 blocks, XCD remap: r8=bid&7, q=bid>>3; co0=(q&7)*64, pair=(q>>3)|(r8<<4)
// 512 thr / 8 waves; wave w owns 64co x 1y(=y0+w) x 64x; acc 4x4 f32x4
#define XB 42240   // 10 rowblk * 66 * 64 B
#define WB 36864   // 9 * 64 * 64 B

__global__ __launch_bounds__(512, 1) void k_conv(
    const __bf16* __restrict__ xs, const __bf16* __restrict__ wb,
    const float* __restrict__ demod, float* __restrict__ out)
{
    __shared__ __align__(128) char smem[2 * XB + 2 * WB];

    const int tid  = threadIdx.x;
    const int lane = tid & 63;
    const int wave = tid >> 6;

    const int bid  = blockIdx.x;
    const int r8   = bid & 7;            // XCD
    const int q    = bid >> 3;
    const int co0  = (q & 7) * 64;
    const int pair = (q >> 3) | (r8 << 4);
    const int y0   = (pair & 7) * 8;
    const int b    = pair >> 3;

    const int m  = lane & 15;
    const int g  = lane >> 4;
    const int qA = g ^ ((m >> 1) & 3);   // W-read quad (lane const)

    // zero x-halo rows (xr=0,65) of all 10 rowblocks in BOTH X buffers: 640 dwords
    for (int i = tid; i < 640; i += 512) {
        int dw = i & 15, h = i >> 4;         // h 0..39
        int buf = h / 20, hh = h % 20;
        int rr = hh >> 1, side = hh & 1;
        ((uint32_t*)smem)[buf * (XB / 4) + (rr * 66 + side * 65) * 16 + dw] = 0;
    }
    asm volatile("s_waitcnt lgkmcnt(0)" ::: "memory");

    f32x4 acc[4][4];
    #pragma unroll
    for (int mi = 0; mi < 4; ++mi)
        #pragma unroll
        for (int nt = 0; nt < 4; ++nt) acc[mi][nt] = (f32x4){0.f, 0.f, 0.f, 0.f};

    // ---- staging: waves 0-3 issue 10 X-ops, waves 4-7 issue 9 W-ops (1 KB each)
    auto stage = [&](int chunk, int sel) {
        if (wave < 4) {
            const __bf16* xsc = xs + ((size_t)chunk * 16 + b) * (66 * 64 * 32);
            #pragma unroll
            for (int i = 0; i < 10; ++i) {
                int o = wave * 10 + i;           // 0..39
                int r = o >> 2, seg = o & 3;
                int p = seg * 64 + lane;
                int xr = 1 + (p >> 2), qd = p & 3;
                int rowg = r * 66 + xr;
                int sq = qd ^ ((rowg >> 1) & 3);
                const __bf16* src = xsc + ((size_t)((y0 + r) * 64 + (xr - 1))) * 32 + sq * 8;
                gload16(src, smem + sel * XB + (r * 66 + 1) * 64 + seg * 1024);
            }
        } else {
            const __bf16* wbc = wb + (size_t)chunk * 9 * CO_ * 32;
            #pragma unroll
            for (int i = 0; i < 9; ++i) {
                int j = (wave - 4) * 9 + i;      // 0..35
                int p = j * 64 + lane;
                int row = p >> 2, qd = p & 3;    // row = t*64+co
                int sq = qd ^ ((row >> 1) & 3);
                const __bf16* src = wbc + ((size_t)((row >> 6) * CO_ + co0 + (row & 63))) * 32 + sq * 8;
                gload16(src, smem + 2 * XB + sel * WB + j * 1024);
            }
        }
    };

    stage(0, 0);

    for (int t = 0; t < 16; ++t) {
        if (t < 15) {
            stage(t + 1, (t + 1) & 1);
            if (wave < 4) asm volatile("s_waitcnt vmcnt(10)" ::: "memory");
            else          asm volatile("s_waitcnt vmcnt(9)"  ::: "memory");
        } else {
            asm volatile("s_waitcnt vmcnt(0)" ::: "memory");
        }
        __builtin_amdgcn_s_barrier();

        const __bf16* ldsX = (const __bf16*)(smem + (t & 1) * XB);
        const __bf16* ldsW = (const __bf16*)(smem + 2 * XB + (t & 1) * WB);

        #pragma unroll
        for (int kh = 0; kh < 3; ++kh) {
            #pragma unroll
            for (int kw = 0; kw < 3; ++kw) {
                const int tp = kh * 3 + kw;
                bf16x8 a0 = *(const bf16x8*)&ldsW[(tp * 64 +  0 + m) * 32 + qA * 8];
                bf16x8 a1 = *(const bf16x8*)&ldsW[(tp * 64 + 16 + m) * 32 + qA * 8];
                bf16x8 a2 = *(const bf16x8*)&ldsW[(tp * 64 + 32 + m) * 32 + qA * 8];
                bf16x8 a3 = *(const bf16x8*)&ldsW[(tp * 64 + 48 + m) * 32 + qA * 8];
                #pragma unroll
                for (int nt = 0; nt < 4; ++nt) {
                    const int rowg = (wave + kh) * 66 + nt * 16 + m + kw;
                    const int qB = g ^ ((rowg >> 1) & 3);
                    bf16x8 bv = *(const bf16x8*)&ldsX[rowg * 32 + qB * 8];
                    acc[0][nt] = __builtin_amdgcn_mfma_f32_16x16x32_bf16(a0, bv, acc[0][nt], 0, 0, 0);
                    acc[1][nt] = __builtin_amdgcn_mfma_f32_16x16x32_bf16(a1, bv, acc[1][nt], 0, 0, 0);
                    acc[2][nt] = __builtin_amdgcn_mfma_f32_16x16x32_bf16(a2, bv, acc[2][nt], 0, 0, 0);
                    acc[3][nt] = __builtin_amdgcn_mfma_f32_16x16x32_bf16(a3, bv, acc[3][nt], 0, 0, 0);
                }
            }
        }
        __builtin_amdgcn_s_barrier();
    }

    // ---- epilogue: out[b][co][y][x] = acc * demod[b][co]
    const int y = y0 + wave;
    #pragma unroll
    for (int mi = 0; mi < 4; ++mi) {
        #pragma unroll
        for (int j = 0; j < 4; ++j) {
            const int co = co0 + mi * 16 + g * 4 + j;
            const float dm = demod[b * CO_ + co];
            float* op = out + ((size_t)(b * CO_ + co) * HH + y) * WW;
            #pragma unroll
            for (int nt = 0; nt < 4; ++nt)
                op[nt * 16 + m] = acc[mi][nt][j] * dm;
        }
    }
}

extern "C" void kernel_launch(void* const* d_in, const int* in_sizes, int n_in,
                              void* d_out, int out_size, void* d_ws, size_t ws_size,
                              hipStream_t stream) {
    const float* x      = (const float*)d_in[0];
    const float* style  = (const float*)d_in[1];
    const float* weight = (const float*)d_in[2];
    const float* mod_w  = (const float*)d_in[3];
    const float* mod_b  = (const float*)d_in[4];
    float* out = (float*)d_out;

    char* wsb = (char*)d_ws;
    float*  s_buf = (float*)(wsb + WS_S);
    float*  demod = (float*)(wsb + WS_DEMOD);
    float*  wsq   = (float*)(wsb + WS_WSQ);
    __bf16* wb    = (__bf16*)(wsb + WS_WB);
    __bf16* xs    = (__bf16*)(wsb + WS_XS);

    k_style<<<dim3(B_), dim3(CI_), 0, stream>>>(style, mod_w, mod_b, s_buf);
    k_wsq<<<dim3(CO_ * CI_ / 512), dim3(512), 0, stream>>>(weight, wsq);
    k_demod<<<dim3(B_), dim3(CO_), 0, stream>>>(s_buf, wsq, demod);
    k_wb<<<dim3(CO_ * CI_ / 256), dim3(256), 0, stream>>>(weight, wb);
    k_guard<<<dim3(2048), dim3(256), 0, stream>>>((uint32_t*)xs);
    k_xs<<<dim3(HH, B_), dim3(256), 0, stream>>>(x, s_buf, xs);
    k_conv<<<dim3(1024), dim3(512), 0, stream>>>(xs, wb, demod, out);
}